// Round 4
// baseline (580.584 us; speedup 1.0000x reference)
//
#include <hip/hip_runtime.h>

// ---- problem constants (from reference) ----
#define NB 2
#define NT 3
#define NCAM 6
#define NC 16
#define FD 48
#define FH 24
#define FW 64
#define GX 100
#define GY 100
#define GZ 8
#define OC 40
#define NVOX (GX * GY * GZ)          // 80000  (divisible by 64 -> bt, b wave-uniform)
#define FSZ (FD * FH * FW)           // 73728 voxels per channel volume
#define CAMSZ (NC * FSZ)             // per-camera feature volume (orig layout)
#define BTSZ (NCAM * CAMSZ)          // per-(b,t) feature block (orig layout)
#define HSZ ((size_t)NB * NT * OC * NVOX)             // 19,200,000 elems
#define FT_ELEMS ((size_t)NB * NT * NCAM * FSZ * NC)  // 42,467,328

static __device__ __forceinline__ unsigned short f2bf_rne(float x) {
    unsigned int u = __float_as_uint(x);
    unsigned int r = (u + 0x7fffu + ((u >> 16) & 1u)) >> 16;
    return (unsigned short)r;
}
static __device__ __forceinline__ float bf_lo(unsigned int u) {
    return __uint_as_float(u << 16);
}
static __device__ __forceinline__ float bf_hi(unsigned int u) {
    return __uint_as_float(u & 0xffff0000u);
}

// Bijective XCD-aware block swizzle (contiguous chunk per XCD; m204 form).
// MI355X has 8 XCDs; default dispatch round-robins blockIdx across them.
static __device__ __forceinline__ int xcd_swizzle(int bid, int nwg) {
    int xcd = bid & 7;
    int local = bid >> 3;
    int q = nwg >> 3, r = nwg & 7;
    return (xcd < r ? xcd * (q + 1) : r * (q + 1) + (xcd - r) * q) + local;
}

// ----------------------------------------------------------------------------
// Setup math (device helper): P[b,t,n] = intrins[b] @ RT[b,t,n][:3,:]  (3x4)
// theta[b,t] cumulative affine (3x4): t=2 -> I, t=1 -> M4[b,1],
// t=0 -> M4[b,0] @ M4[b,1]
// ----------------------------------------------------------------------------
static __device__ __forceinline__ void do_setup(
    int tid, const float* __restrict__ RT, const float* __restrict__ intrins,
    const float* __restrict__ DoF, float* __restrict__ P,
    float* __restrict__ theta) {
    if (tid < NB * NT * NCAM) {
        int bt = tid / NCAM;
        int b = bt / NT;
        const float* I3 = intrins + b * 9;
        const float* R = RT + (size_t)tid * 16;
        float* Pp = P + tid * 12;
        for (int r = 0; r < 3; ++r)
            for (int c = 0; c < 4; ++c) {
                float s = 0.f;
                for (int k = 0; k < 3; ++k) s += I3[r * 3 + k] * R[k * 4 + c];
                Pp[r * 4 + c] = s;
            }
    }
    if (tid >= 64 && tid < 64 + NB) {
        int b = tid - 64;
        const float* D0 = DoF + (size_t)(b * NT + 0) * 16;
        const float* D1 = DoF + (size_t)(b * NT + 1) * 16;
        float* th = theta + (size_t)b * NT * 12;
        for (int i = 0; i < 12; ++i) th[2 * 12 + i] = 0.f;
        th[2 * 12 + 0] = 1.f; th[2 * 12 + 5] = 1.f; th[2 * 12 + 10] = 1.f;
        for (int i = 0; i < 12; ++i) th[1 * 12 + i] = D1[i];
        for (int r = 0; r < 3; ++r)
            for (int c = 0; c < 4; ++c) {
                float s = (c == 3) ? D0[r * 4 + 3] : 0.f;
                for (int k = 0; k < 3; ++k) s += D0[r * 4 + k] * D1[k * 4 + c];
                th[0 * 12 + r * 4 + c] = s;
            }
    }
}

__global__ void setup_kernel(const float* __restrict__ RT,
                             const float* __restrict__ intrins,
                             const float* __restrict__ DoF,
                             float* __restrict__ P,
                             float* __restrict__ theta) {
    do_setup(threadIdx.x, RT, intrins, DoF, P, theta);
}

// ----------------------------------------------------------------------------
// Transpose features (B,T,N,C,FD,FH,FW) -> [btn][pos][C16] channel-last
// (fp32 or bf16 output). Block 0 additionally performs setup (fused dispatch;
// sample_mlp1 only launches after this kernel completes, so P/theta are ready).
// ----------------------------------------------------------------------------
template <typename FT>
__global__ __launch_bounds__(256) void transpose_feat(
    const float* __restrict__ feat, FT* __restrict__ ft,
    const float* __restrict__ RT, const float* __restrict__ intrins,
    const float* __restrict__ DoF, float* __restrict__ P,
    float* __restrict__ theta) {
    if (blockIdx.x == 0) do_setup(threadIdx.x, RT, intrins, DoF, P, theta);
    size_t tid = (size_t)blockIdx.x * 256 + threadIdx.x;
    int pos = (int)(tid % FSZ);
    int btn = (int)(tid / FSZ);
    const float* src = feat + (size_t)btn * CAMSZ + pos;
    float v[NC];
#pragma unroll
    for (int c = 0; c < NC; ++c) v[c] = src[(size_t)c * FSZ];
    if constexpr (sizeof(FT) == 4) {
        float4* dst = reinterpret_cast<float4*>(
            (float*)ft + ((size_t)btn * FSZ + pos) * NC);
#pragma unroll
        for (int q = 0; q < 4; ++q)
            dst[q] = make_float4(v[4 * q], v[4 * q + 1], v[4 * q + 2], v[4 * q + 3]);
    } else {
        unsigned int packed[8];
#pragma unroll
        for (int j = 0; j < 8; ++j)
            packed[j] = (unsigned int)f2bf_rne(v[2 * j]) |
                        ((unsigned int)f2bf_rne(v[2 * j + 1]) << 16);
        uint4* dst = reinterpret_cast<uint4*>(
            (unsigned short*)ft + ((size_t)btn * FSZ + pos) * NC);
        dst[0] = make_uint4(packed[0], packed[1], packed[2], packed[3]);
        dst[1] = make_uint4(packed[4], packed[5], packed[6], packed[7]);
    }
}

// ----------------------------------------------------------------------------
// Kernel 1: frustum trilinear sample (6 cams x 16 ch) + W_N matvec + ReLU -> h
// One thread per (b,t,voxel), sequential 6-cam loop, fp32 float4 gather
// (bf16 gather regressed: VALU unpack), per-cam validity early-out (~75% of
// voxels outside every cam's frustum -> wave-coherent skip).
// h layout: [bt][vid][OC] bf16  (vid = gx*GZ*GY + gz*GY + gy)
// ----------------------------------------------------------------------------
template <typename FT, bool CHLAST>
__global__ __launch_bounds__(256) void sample_mlp1(
    const float* __restrict__ feat,   // original layout (used when !CHLAST)
    const FT* __restrict__ ft,        // channel-last (used when CHLAST)
    const float* __restrict__ P,
    const float* __restrict__ W_N,
    const float* __restrict__ b_N,
    unsigned short* __restrict__ h) {
    int bid = xcd_swizzle(blockIdx.x, gridDim.x);
    int tid = bid * 256 + threadIdx.x;
    int vid = tid % NVOX;
    int bt = __builtin_amdgcn_readfirstlane(tid / NVOX);  // wave-uniform (NVOX%64==0)
    int gy = vid % GY;
    int r2 = vid / GY;
    int gz = r2 % GZ;
    int gx = r2 / GZ;
    float X = (float)gx - 49.5f;
    float Y = (float)gy - 49.5f;
    float Z = (float)gz - 2.5f;

    float acc[OC];
#pragma unroll
    for (int o = 0; o < OC; ++o) acc[o] = b_N[o];

    for (int n = 0; n < NCAM; ++n) {
        const float* Pp = P + (bt * NCAM + n) * 12;
        float px = Pp[0] * X + Pp[1] * Y + Pp[2] * Z + Pp[3];
        float py = Pp[4] * X + Pp[5] * Y + Pp[6] * Z + Pp[7];
        float pz = Pp[8] * X + Pp[9] * Y + Pp[10] * Z + Pp[11];
        float zc = fmaxf(pz, 1e-5f);
        float ix = px / zc;                       // = u (normalization round-trips)
        float iy = py / zc;
        float iz = (pz - 2.0f) * (48.0f / 44.8f); // = dbin

        // exact early-out: outside the open box, every corner weight is zero
        bool cam_valid = (ix > -1.f) & (ix < (float)FW) &
                         (iy > -1.f) & (iy < (float)FH) &
                         (iz > -1.f) & (iz < (float)FD);
        if (!cam_valid) continue;

        float x0 = floorf(ix), y0 = floorf(iy), z0 = floorf(iz);
        float wx1 = ix - x0, wy1 = iy - y0, wz1 = iz - z0;
        float wx0 = 1.f - wx1, wy0 = 1.f - wy1, wz0 = 1.f - wz1;

        float w8[8];
        int off8[8];
#pragma unroll
        for (int k = 0; k < 8; ++k) {
            float xf = x0 + (float)(k & 1);
            float yf = y0 + (float)((k >> 1) & 1);
            float zf = z0 + (float)(k >> 2);
            bool valid = (xf >= 0.f) & (xf <= (float)(FW - 1)) &
                         (yf >= 0.f) & (yf <= (float)(FH - 1)) &
                         (zf >= 0.f) & (zf <= (float)(FD - 1));
            int xi = (int)fminf(fmaxf(xf, 0.f), (float)(FW - 1));
            int yi = (int)fminf(fmaxf(yf, 0.f), (float)(FH - 1));
            int zi = (int)fminf(fmaxf(zf, 0.f), (float)(FD - 1));
            float w = ((k & 1) ? wx1 : wx0) * (((k >> 1) & 1) ? wy1 : wy0) *
                      ((k >> 2) ? wz1 : wz0);
            w8[k] = valid ? w : 0.f;
            off8[k] = (zi * FH + yi) * FW + xi;
        }

        float s[NC];
#pragma unroll
        for (int c = 0; c < NC; ++c) s[c] = 0.f;

        if constexpr (CHLAST) {
            const size_t camBase = (size_t)(bt * NCAM + n) * FSZ;
            if constexpr (sizeof(FT) == 4) {
#pragma unroll
                for (int k = 0; k < 8; ++k) {
                    float w = w8[k];
                    const float4* cp = reinterpret_cast<const float4*>(
                        (const float*)ft + (camBase + (size_t)off8[k]) * NC);
#pragma unroll
                    for (int q = 0; q < 4; ++q) {
                        float4 v = cp[q];
                        s[4 * q + 0] = fmaf(w, v.x, s[4 * q + 0]);
                        s[4 * q + 1] = fmaf(w, v.y, s[4 * q + 1]);
                        s[4 * q + 2] = fmaf(w, v.z, s[4 * q + 2]);
                        s[4 * q + 3] = fmaf(w, v.w, s[4 * q + 3]);
                    }
                }
            } else {
#pragma unroll
                for (int k = 0; k < 8; ++k) {
                    float w = w8[k];
                    const uint4* cp = reinterpret_cast<const uint4*>(
                        (const unsigned short*)ft + (camBase + (size_t)off8[k]) * NC);
                    uint4 a = cp[0], b2 = cp[1];
                    unsigned int uu[8] = {a.x, a.y, a.z, a.w, b2.x, b2.y, b2.z, b2.w};
#pragma unroll
                    for (int j = 0; j < 8; ++j) {
                        s[2 * j + 0] = fmaf(w, bf_lo(uu[j]), s[2 * j + 0]);
                        s[2 * j + 1] = fmaf(w, bf_hi(uu[j]), s[2 * j + 1]);
                    }
                }
            }
        } else {
            const float* fn = feat + (size_t)bt * BTSZ + (size_t)n * CAMSZ;
#pragma unroll
            for (int c = 0; c < NC; ++c) {
                const float* fc = fn + (size_t)c * FSZ;
                float v = 0.f;
#pragma unroll
                for (int k = 0; k < 8; ++k) v = fmaf(w8[k], fc[off8[k]], v);
                s[c] = v;
            }
        }

        // acc[o] += W_N[o, n*16 + c] * s[c]
#pragma unroll
        for (int o = 0; o < OC; ++o) {
            const float4* w4 =
                reinterpret_cast<const float4*>(W_N + o * (NCAM * NC) + n * NC);
#pragma unroll
            for (int q = 0; q < 4; ++q) {
                float4 w = w4[q];
                acc[o] = fmaf(w.x, s[4 * q + 0], acc[o]);
                acc[o] = fmaf(w.y, s[4 * q + 1], acc[o]);
                acc[o] = fmaf(w.z, s[4 * q + 2], acc[o]);
                acc[o] = fmaf(w.w, s[4 * q + 3], acc[o]);
            }
        }
    }

    // ReLU + pack to bf16, store 80B (5 x uint4)
    unsigned int u[20];
#pragma unroll
    for (int j = 0; j < 20; ++j)
        u[j] = (unsigned int)f2bf_rne(fmaxf(acc[2 * j], 0.f)) |
               ((unsigned int)f2bf_rne(fmaxf(acc[2 * j + 1], 0.f)) << 16);
    uint4* d4 = reinterpret_cast<uint4*>(
        h + ((size_t)bt * NVOX + (size_t)vid) * OC);
#pragma unroll
    for (int q = 0; q < 5; ++q)
        d4[q] = make_uint4(u[4 * q], u[4 * q + 1], u[4 * q + 2], u[4 * q + 3]);
}

// ----------------------------------------------------------------------------
// Kernel 2: temporal affine warp (trilinear on bf16 channel-last h) + W_T + ReLU
// One thread per (b,voxel). LATENCY FIX: grid is only 625 blocks (2.4 waves/
// SIMD), so occupancy is grid-limited -> registers are free. launch_bounds
// (256,2) + batched gather: all 40 corner loads of a t issued into registers
// before any unpack/FMA (memory-level parallelism ~40 vs ~8), t=2 passthrough
// prefetched at kernel top. XCD swizzle keeps gather neighborhoods in one L2.
// out layout: [b][o][d][h][w] = (B,40,100,8,100)
// ----------------------------------------------------------------------------
__global__ __launch_bounds__(256, 2) void warp_mlp2(
    const unsigned short* __restrict__ h,
    const float* __restrict__ theta,
    const float* __restrict__ W_T,
    const float* __restrict__ b_T,
    float* __restrict__ out) {
    int bid = xcd_swizzle(blockIdx.x, gridDim.x);
    int tid = bid * 256 + threadIdx.x;
    int vid = tid % NVOX;
    int b = __builtin_amdgcn_readfirstlane(tid / NVOX);  // wave-uniform
    int w_ = vid % GY;        // Wp = 100
    int r2 = vid / GY;
    int h_ = r2 % GZ;         // Hp = 8
    int d_ = r2 / GZ;         // Dp = 100

    float xg = -1.f + 2.f * (float)w_ / 99.f;
    float yg = -1.f + 2.f * (float)h_ / 7.f;
    float zg = -1.f + 2.f * (float)d_ / 99.f;

    // ---- t = 2 identity pass-through: prefetch 80B now, consume at the end
    uint4 p2[5];
    {
        const uint4* cp2 = reinterpret_cast<const uint4*>(
            h + ((size_t)(b * NT + 2) * NVOX + (size_t)vid) * OC);
#pragma unroll
        for (int q = 0; q < 5; ++q) p2[q] = cp2[q];
    }

    float acc[OC];
#pragma unroll
    for (int o = 0; o < OC; ++o) acc[o] = b_T[o];

    // ---- t = 0, 1: full trilinear gather, loads batched per t ----
    for (int t = 0; t < 2; ++t) {
        const float* th = theta + (b * NT + t) * 12;
        float g0 = th[0] * xg + th[1] * yg + th[2] * zg + th[3];
        float g1 = th[4] * xg + th[5] * yg + th[6] * zg + th[7];
        float g2 = th[8] * xg + th[9] * yg + th[10] * zg + th[11];
        float ix = (g0 + 1.f) * 0.5f * 99.f;
        float iy = (g1 + 1.f) * 0.5f * 7.f;
        float iz = (g2 + 1.f) * 0.5f * 99.f;
        float x0 = floorf(ix), y0 = floorf(iy), z0 = floorf(iz);
        float wx1 = ix - x0, wy1 = iy - y0, wz1 = iz - z0;
        float wx0 = 1.f - wx1, wy0 = 1.f - wy1, wz0 = 1.f - wz1;

        float w8[8];
        int off8[8];
#pragma unroll
        for (int k = 0; k < 8; ++k) {
            float xf = x0 + (float)(k & 1);
            float yf = y0 + (float)((k >> 1) & 1);
            float zf = z0 + (float)(k >> 2);
            bool valid = (xf >= 0.f) & (xf <= 99.f) &
                         (yf >= 0.f) & (yf <= 7.f) &
                         (zf >= 0.f) & (zf <= 99.f);
            int xi = (int)fminf(fmaxf(xf, 0.f), 99.f);
            int yi = (int)fminf(fmaxf(yf, 0.f), 7.f);
            int zi = (int)fminf(fmaxf(zf, 0.f), 99.f);
            float w = ((k & 1) ? wx1 : wx0) * (((k >> 1) & 1) ? wy1 : wy0) *
                      ((k >> 2) ? wz1 : wz0);
            w8[k] = valid ? w : 0.f;
            off8[k] = (zi * GZ + yi) * GY + xi;  // voxel index in [vid] space
        }

        const unsigned short* hb = h + (size_t)(b * NT + t) * NVOX * OC;

        // batch-issue all 8 corners x 5 uint4 loads (static indices -> regs)
        uint4 rr[8][5];
#pragma unroll
        for (int k = 0; k < 8; ++k) {
            const uint4* cp =
                reinterpret_cast<const uint4*>(hb + (size_t)off8[k] * OC);
#pragma unroll
            for (int q = 0; q < 5; ++q) rr[k][q] = cp[q];
        }

        float sval[OC];
#pragma unroll
        for (int o2 = 0; o2 < OC; ++o2) sval[o2] = 0.f;
#pragma unroll
        for (int k = 0; k < 8; ++k) {
            float w = w8[k];
#pragma unroll
            for (int q = 0; q < 5; ++q) {
                uint4 a = rr[k][q];
                sval[8 * q + 0] = fmaf(w, bf_lo(a.x), sval[8 * q + 0]);
                sval[8 * q + 1] = fmaf(w, bf_hi(a.x), sval[8 * q + 1]);
                sval[8 * q + 2] = fmaf(w, bf_lo(a.y), sval[8 * q + 2]);
                sval[8 * q + 3] = fmaf(w, bf_hi(a.y), sval[8 * q + 3]);
                sval[8 * q + 4] = fmaf(w, bf_lo(a.z), sval[8 * q + 4]);
                sval[8 * q + 5] = fmaf(w, bf_hi(a.z), sval[8 * q + 5]);
                sval[8 * q + 6] = fmaf(w, bf_lo(a.w), sval[8 * q + 6]);
                sval[8 * q + 7] = fmaf(w, bf_hi(a.w), sval[8 * q + 7]);
            }
        }

        // acc[o] += W_T[o, t*40 + o2] * sval[o2]
#pragma unroll
        for (int o = 0; o < OC; ++o) {
            const float4* w4 =
                reinterpret_cast<const float4*>(W_T + o * (NT * OC) + t * OC);
#pragma unroll
            for (int q = 0; q < 10; ++q) {
                float4 w = w4[q];
                acc[o] = fmaf(w.x, sval[4 * q + 0], acc[o]);
                acc[o] = fmaf(w.y, sval[4 * q + 1], acc[o]);
                acc[o] = fmaf(w.z, sval[4 * q + 2], acc[o]);
                acc[o] = fmaf(w.w, sval[4 * q + 3], acc[o]);
            }
        }
    }

    // ---- t = 2: consume the prefetched pass-through row ----
    {
        float sval[OC];
#pragma unroll
        for (int q = 0; q < 5; ++q) {
            uint4 a = p2[q];
            sval[8 * q + 0] = bf_lo(a.x);
            sval[8 * q + 1] = bf_hi(a.x);
            sval[8 * q + 2] = bf_lo(a.y);
            sval[8 * q + 3] = bf_hi(a.y);
            sval[8 * q + 4] = bf_lo(a.z);
            sval[8 * q + 5] = bf_hi(a.z);
            sval[8 * q + 6] = bf_lo(a.w);
            sval[8 * q + 7] = bf_hi(a.w);
        }
#pragma unroll
        for (int o = 0; o < OC; ++o) {
            const float4* w4 =
                reinterpret_cast<const float4*>(W_T + o * (NT * OC) + 2 * OC);
#pragma unroll
            for (int q = 0; q < 10; ++q) {
                float4 w = w4[q];
                acc[o] = fmaf(w.x, sval[4 * q + 0], acc[o]);
                acc[o] = fmaf(w.y, sval[4 * q + 1], acc[o]);
                acc[o] = fmaf(w.z, sval[4 * q + 2], acc[o]);
                acc[o] = fmaf(w.w, sval[4 * q + 3], acc[o]);
            }
        }
    }

    // per-o planes: lanes have consecutive vid -> coalesced per o
    float* op = out + (size_t)b * OC * NVOX + vid;
#pragma unroll
    for (int o = 0; o < OC; ++o) op[(size_t)o * NVOX] = fmaxf(acc[o], 0.f);
}

extern "C" void kernel_launch(void* const* d_in, const int* in_sizes, int n_in,
                              void* d_out, int out_size, void* d_ws, size_t ws_size,
                              hipStream_t stream) {
    const float* frustum = (const float*)d_in[0];
    const float* RT      = (const float*)d_in[1];
    const float* intrins = (const float*)d_in[2];
    const float* DoF     = (const float*)d_in[3];
    const float* W_N     = (const float*)d_in[4];
    const float* b_N     = (const float*)d_in[5];
    const float* W_T     = (const float*)d_in[6];
    const float* b_T     = (const float*)d_in[7];
    float* out = (float*)d_out;

    const size_t ft_f32  = FT_ELEMS * sizeof(float);          // ~170 MB
    const size_t ft_bf16 = FT_ELEMS * sizeof(unsigned short); // ~85 MB
    const size_t h_bytes = HSZ * sizeof(unsigned short);      // ~38.4 MB
    const size_t small = 4096;                                // P + theta

    char* base = (char*)d_ws;
    int mode;  // 0 = fp32 chlast, 1 = bf16 chlast, 2 = no transpose
    size_t ft_bytes;
    if (ws_size >= ft_f32 + h_bytes + small) { mode = 0; ft_bytes = ft_f32; }
    else if (ws_size >= ft_bf16 + h_bytes + small) { mode = 1; ft_bytes = ft_bf16; }
    else { mode = 2; ft_bytes = 0; }

    size_t ft_al = (ft_bytes + 255) & ~(size_t)255;
    void* ft_buf = base;
    unsigned short* h_buf = (unsigned short*)(base + ft_al);
    float* P_buf = (float*)(base + ft_al + ((h_bytes + 255) & ~(size_t)255));
    float* th_buf = P_buf + NB * NT * NCAM * 12;

    const int tr_blocks = (NB * NT * NCAM * FSZ) / 256;  // 10368
    const int n1_blocks = (NB * NT * NVOX) / 256;        // 1875
    const int n2_blocks = (NB * NVOX) / 256;             // 625

    if (mode == 0) {
        transpose_feat<float><<<tr_blocks, 256, 0, stream>>>(
            frustum, (float*)ft_buf, RT, intrins, DoF, P_buf, th_buf);
        sample_mlp1<float, true><<<n1_blocks, 256, 0, stream>>>(
            frustum, (const float*)ft_buf, P_buf, W_N, b_N, h_buf);
    } else if (mode == 1) {
        transpose_feat<unsigned short><<<tr_blocks, 256, 0, stream>>>(
            frustum, (unsigned short*)ft_buf, RT, intrins, DoF, P_buf, th_buf);
        sample_mlp1<unsigned short, true><<<n1_blocks, 256, 0, stream>>>(
            frustum, (const unsigned short*)ft_buf, P_buf, W_N, b_N, h_buf);
    } else {
        setup_kernel<<<1, 128, 0, stream>>>(RT, intrins, DoF, P_buf, th_buf);
        sample_mlp1<float, false><<<n1_blocks, 256, 0, stream>>>(
            frustum, (const float*)nullptr, P_buf, W_N, b_N, h_buf);
    }

    warp_mlp2<<<n2_blocks, 256, 0, stream>>>(h_buf, th_buf, W_T, b_T, out);
}

// Round 5
// 457.578 us; speedup vs baseline: 1.2688x; 1.2688x over previous
//
#include <hip/hip_runtime.h>

// ---- problem constants (from reference) ----
#define NB 2
#define NT 3
#define NCAM 6
#define NC 16
#define FD 48
#define FH 24
#define FW 64
#define GX 100
#define GY 100
#define GZ 8
#define OC 40
#define NVOX (GX * GY * GZ)          // 80000  (divisible by 64 -> bt, b wave-uniform)
#define FSZ (FD * FH * FW)           // 73728 voxels per channel volume
#define CAMSZ (NC * FSZ)             // per-camera feature volume (orig layout)
#define BTSZ (NCAM * CAMSZ)          // per-(b,t) feature block (orig layout)
#define HSZ ((size_t)NB * NT * OC * NVOX)             // 19,200,000 elems
#define FT_ELEMS ((size_t)NB * NT * NCAM * FSZ * NC)  // 42,467,328

static __device__ __forceinline__ unsigned short f2bf_rne(float x) {
    unsigned int u = __float_as_uint(x);
    unsigned int r = (u + 0x7fffu + ((u >> 16) & 1u)) >> 16;
    return (unsigned short)r;
}
static __device__ __forceinline__ float bf_lo(unsigned int u) {
    return __uint_as_float(u << 16);
}
static __device__ __forceinline__ float bf_hi(unsigned int u) {
    return __uint_as_float(u & 0xffff0000u);
}

// Bijective XCD-aware block swizzle (contiguous chunk per XCD; m204 form).
// Applied ONLY to warp_mlp2: round-4 evidence (FETCH 75->23 MB) shows it fixes
// gather L2 locality there. (Round-4's regression was the batched-load scratch
// spill -- WRITE grew by exactly the spill bytes -- not the swizzle.)
static __device__ __forceinline__ int xcd_swizzle(int bid, int nwg) {
    int xcd = bid & 7;
    int local = bid >> 3;
    int q = nwg >> 3, r = nwg & 7;
    return (xcd < r ? xcd * (q + 1) : r * (q + 1) + (xcd - r) * q) + local;
}

// ----------------------------------------------------------------------------
// Setup math (device helper): P[b,t,n] = intrins[b] @ RT[b,t,n][:3,:]  (3x4)
// theta[b,t] cumulative affine (3x4): t=2 -> I, t=1 -> M4[b,1],
// t=0 -> M4[b,0] @ M4[b,1]
// ----------------------------------------------------------------------------
static __device__ __forceinline__ void do_setup(
    int tid, const float* __restrict__ RT, const float* __restrict__ intrins,
    const float* __restrict__ DoF, float* __restrict__ P,
    float* __restrict__ theta) {
    if (tid < NB * NT * NCAM) {
        int bt = tid / NCAM;
        int b = bt / NT;
        const float* I3 = intrins + b * 9;
        const float* R = RT + (size_t)tid * 16;
        float* Pp = P + tid * 12;
        for (int r = 0; r < 3; ++r)
            for (int c = 0; c < 4; ++c) {
                float s = 0.f;
                for (int k = 0; k < 3; ++k) s += I3[r * 3 + k] * R[k * 4 + c];
                Pp[r * 4 + c] = s;
            }
    }
    if (tid >= 64 && tid < 64 + NB) {
        int b = tid - 64;
        const float* D0 = DoF + (size_t)(b * NT + 0) * 16;
        const float* D1 = DoF + (size_t)(b * NT + 1) * 16;
        float* th = theta + (size_t)b * NT * 12;
        for (int i = 0; i < 12; ++i) th[2 * 12 + i] = 0.f;
        th[2 * 12 + 0] = 1.f; th[2 * 12 + 5] = 1.f; th[2 * 12 + 10] = 1.f;
        for (int i = 0; i < 12; ++i) th[1 * 12 + i] = D1[i];
        for (int r = 0; r < 3; ++r)
            for (int c = 0; c < 4; ++c) {
                float s = (c == 3) ? D0[r * 4 + 3] : 0.f;
                for (int k = 0; k < 3; ++k) s += D0[r * 4 + k] * D1[k * 4 + c];
                th[0 * 12 + r * 4 + c] = s;
            }
    }
}

__global__ void setup_kernel(const float* __restrict__ RT,
                             const float* __restrict__ intrins,
                             const float* __restrict__ DoF,
                             float* __restrict__ P,
                             float* __restrict__ theta) {
    do_setup(threadIdx.x, RT, intrins, DoF, P, theta);
}

// ----------------------------------------------------------------------------
// Transpose features (B,T,N,C,FD,FH,FW) -> [btn][pos][C16] channel-last
// (fp32 or bf16 output). Block 0 additionally performs setup (fused dispatch;
// sample_mlp1 only launches after this kernel completes, so P/theta are ready).
// ----------------------------------------------------------------------------
template <typename FT>
__global__ __launch_bounds__(256) void transpose_feat(
    const float* __restrict__ feat, FT* __restrict__ ft,
    const float* __restrict__ RT, const float* __restrict__ intrins,
    const float* __restrict__ DoF, float* __restrict__ P,
    float* __restrict__ theta) {
    if (blockIdx.x == 0) do_setup(threadIdx.x, RT, intrins, DoF, P, theta);
    size_t tid = (size_t)blockIdx.x * 256 + threadIdx.x;
    int pos = (int)(tid % FSZ);
    int btn = (int)(tid / FSZ);
    const float* src = feat + (size_t)btn * CAMSZ + pos;
    float v[NC];
#pragma unroll
    for (int c = 0; c < NC; ++c) v[c] = src[(size_t)c * FSZ];
    if constexpr (sizeof(FT) == 4) {
        float4* dst = reinterpret_cast<float4*>(
            (float*)ft + ((size_t)btn * FSZ + pos) * NC);
#pragma unroll
        for (int q = 0; q < 4; ++q)
            dst[q] = make_float4(v[4 * q], v[4 * q + 1], v[4 * q + 2], v[4 * q + 3]);
    } else {
        unsigned int packed[8];
#pragma unroll
        for (int j = 0; j < 8; ++j)
            packed[j] = (unsigned int)f2bf_rne(v[2 * j]) |
                        ((unsigned int)f2bf_rne(v[2 * j + 1]) << 16);
        uint4* dst = reinterpret_cast<uint4*>(
            (unsigned short*)ft + ((size_t)btn * FSZ + pos) * NC);
        dst[0] = make_uint4(packed[0], packed[1], packed[2], packed[3]);
        dst[1] = make_uint4(packed[4], packed[5], packed[6], packed[7]);
    }
}

// ----------------------------------------------------------------------------
// Kernel 1: frustum trilinear sample (6 cams x 16 ch) + W_N matvec + ReLU -> h
// One thread per (b,t,voxel), sequential 6-cam loop, fp32 float4 gather
// (bf16 gather regressed: VALU unpack), per-cam validity early-out (~75% of
// voxels outside every cam's frustum -> wave-coherent skip). No block swizzle
// (round-4 confound; revert to round-3 exact form).
// h layout: [bt][vid][OC] bf16  (vid = gx*GZ*GY + gz*GY + gy)
// ----------------------------------------------------------------------------
template <typename FT, bool CHLAST>
__global__ __launch_bounds__(256) void sample_mlp1(
    const float* __restrict__ feat,   // original layout (used when !CHLAST)
    const FT* __restrict__ ft,        // channel-last (used when CHLAST)
    const float* __restrict__ P,
    const float* __restrict__ W_N,
    const float* __restrict__ b_N,
    unsigned short* __restrict__ h) {
    int tid = blockIdx.x * 256 + threadIdx.x;
    int vid = tid % NVOX;
    int bt = __builtin_amdgcn_readfirstlane(tid / NVOX);  // wave-uniform (NVOX%64==0)
    int gy = vid % GY;
    int r2 = vid / GY;
    int gz = r2 % GZ;
    int gx = r2 / GZ;
    float X = (float)gx - 49.5f;
    float Y = (float)gy - 49.5f;
    float Z = (float)gz - 2.5f;

    float acc[OC];
#pragma unroll
    for (int o = 0; o < OC; ++o) acc[o] = b_N[o];

    for (int n = 0; n < NCAM; ++n) {
        const float* Pp = P + (bt * NCAM + n) * 12;
        float px = Pp[0] * X + Pp[1] * Y + Pp[2] * Z + Pp[3];
        float py = Pp[4] * X + Pp[5] * Y + Pp[6] * Z + Pp[7];
        float pz = Pp[8] * X + Pp[9] * Y + Pp[10] * Z + Pp[11];
        float zc = fmaxf(pz, 1e-5f);
        float ix = px / zc;                       // = u (normalization round-trips)
        float iy = py / zc;
        float iz = (pz - 2.0f) * (48.0f / 44.8f); // = dbin

        // exact early-out: outside the open box, every corner weight is zero
        bool cam_valid = (ix > -1.f) & (ix < (float)FW) &
                         (iy > -1.f) & (iy < (float)FH) &
                         (iz > -1.f) & (iz < (float)FD);
        if (!cam_valid) continue;

        float x0 = floorf(ix), y0 = floorf(iy), z0 = floorf(iz);
        float wx1 = ix - x0, wy1 = iy - y0, wz1 = iz - z0;
        float wx0 = 1.f - wx1, wy0 = 1.f - wy1, wz0 = 1.f - wz1;

        float w8[8];
        int off8[8];
#pragma unroll
        for (int k = 0; k < 8; ++k) {
            float xf = x0 + (float)(k & 1);
            float yf = y0 + (float)((k >> 1) & 1);
            float zf = z0 + (float)(k >> 2);
            bool valid = (xf >= 0.f) & (xf <= (float)(FW - 1)) &
                         (yf >= 0.f) & (yf <= (float)(FH - 1)) &
                         (zf >= 0.f) & (zf <= (float)(FD - 1));
            int xi = (int)fminf(fmaxf(xf, 0.f), (float)(FW - 1));
            int yi = (int)fminf(fmaxf(yf, 0.f), (float)(FH - 1));
            int zi = (int)fminf(fmaxf(zf, 0.f), (float)(FD - 1));
            float w = ((k & 1) ? wx1 : wx0) * (((k >> 1) & 1) ? wy1 : wy0) *
                      ((k >> 2) ? wz1 : wz0);
            w8[k] = valid ? w : 0.f;
            off8[k] = (zi * FH + yi) * FW + xi;
        }

        float s[NC];
#pragma unroll
        for (int c = 0; c < NC; ++c) s[c] = 0.f;

        if constexpr (CHLAST) {
            const size_t camBase = (size_t)(bt * NCAM + n) * FSZ;
            if constexpr (sizeof(FT) == 4) {
#pragma unroll
                for (int k = 0; k < 8; ++k) {
                    float w = w8[k];
                    const float4* cp = reinterpret_cast<const float4*>(
                        (const float*)ft + (camBase + (size_t)off8[k]) * NC);
#pragma unroll
                    for (int q = 0; q < 4; ++q) {
                        float4 v = cp[q];
                        s[4 * q + 0] = fmaf(w, v.x, s[4 * q + 0]);
                        s[4 * q + 1] = fmaf(w, v.y, s[4 * q + 1]);
                        s[4 * q + 2] = fmaf(w, v.z, s[4 * q + 2]);
                        s[4 * q + 3] = fmaf(w, v.w, s[4 * q + 3]);
                    }
                }
            } else {
#pragma unroll
                for (int k = 0; k < 8; ++k) {
                    float w = w8[k];
                    const uint4* cp = reinterpret_cast<const uint4*>(
                        (const unsigned short*)ft + (camBase + (size_t)off8[k]) * NC);
                    uint4 a = cp[0], b2 = cp[1];
                    unsigned int uu[8] = {a.x, a.y, a.z, a.w, b2.x, b2.y, b2.z, b2.w};
#pragma unroll
                    for (int j = 0; j < 8; ++j) {
                        s[2 * j + 0] = fmaf(w, bf_lo(uu[j]), s[2 * j + 0]);
                        s[2 * j + 1] = fmaf(w, bf_hi(uu[j]), s[2 * j + 1]);
                    }
                }
            }
        } else {
            const float* fn = feat + (size_t)bt * BTSZ + (size_t)n * CAMSZ;
#pragma unroll
            for (int c = 0; c < NC; ++c) {
                const float* fc = fn + (size_t)c * FSZ;
                float v = 0.f;
#pragma unroll
                for (int k = 0; k < 8; ++k) v = fmaf(w8[k], fc[off8[k]], v);
                s[c] = v;
            }
        }

        // acc[o] += W_N[o, n*16 + c] * s[c]
#pragma unroll
        for (int o = 0; o < OC; ++o) {
            const float4* w4 =
                reinterpret_cast<const float4*>(W_N + o * (NCAM * NC) + n * NC);
#pragma unroll
            for (int q = 0; q < 4; ++q) {
                float4 w = w4[q];
                acc[o] = fmaf(w.x, s[4 * q + 0], acc[o]);
                acc[o] = fmaf(w.y, s[4 * q + 1], acc[o]);
                acc[o] = fmaf(w.z, s[4 * q + 2], acc[o]);
                acc[o] = fmaf(w.w, s[4 * q + 3], acc[o]);
            }
        }
    }

    // ReLU + pack to bf16, store 80B (5 x uint4)
    unsigned int u[20];
#pragma unroll
    for (int j = 0; j < 20; ++j)
        u[j] = (unsigned int)f2bf_rne(fmaxf(acc[2 * j], 0.f)) |
               ((unsigned int)f2bf_rne(fmaxf(acc[2 * j + 1], 0.f)) << 16);
    uint4* d4 = reinterpret_cast<uint4*>(
        h + ((size_t)bt * NVOX + (size_t)vid) * OC);
#pragma unroll
    for (int q = 0; q < 5; ++q)
        d4[q] = make_uint4(u[4 * q], u[4 * q + 1], u[4 * q + 2], u[4 * q + 3]);
}

// ----------------------------------------------------------------------------
// Kernel 2: temporal affine warp (trilinear on bf16 channel-last h) + W_T + ReLU
// ROUND-3 BODY exactly (84 VGPR, compiler-scheduled corner loads -- the
// batched-register variant spilled to scratch: WRITE grew +12.3MB, dur 2x).
// ONLY change vs round 3: XCD-aware block swizzle (FETCH 75->23 MB evidence).
// t=2 theta == I -> exact pass-through (single 80B load).
// out layout: [b][o][d][h][w] = (B,40,100,8,100)
// ----------------------------------------------------------------------------
__global__ __launch_bounds__(256) void warp_mlp2(
    const unsigned short* __restrict__ h,
    const float* __restrict__ theta,
    const float* __restrict__ W_T,
    const float* __restrict__ b_T,
    float* __restrict__ out) {
    int bid = xcd_swizzle(blockIdx.x, gridDim.x);
    int tid = bid * 256 + threadIdx.x;
    int vid = tid % NVOX;
    int b = __builtin_amdgcn_readfirstlane(tid / NVOX);  // wave-uniform
    int w_ = vid % GY;        // Wp = 100
    int r2 = vid / GY;
    int h_ = r2 % GZ;         // Hp = 8
    int d_ = r2 / GZ;         // Dp = 100

    float xg = -1.f + 2.f * (float)w_ / 99.f;
    float yg = -1.f + 2.f * (float)h_ / 7.f;
    float zg = -1.f + 2.f * (float)d_ / 99.f;

    float acc[OC];
#pragma unroll
    for (int o = 0; o < OC; ++o) acc[o] = b_T[o];

    // ---- t = 0, 1: full trilinear gather ----
    for (int t = 0; t < 2; ++t) {
        const float* th = theta + (b * NT + t) * 12;
        float g0 = th[0] * xg + th[1] * yg + th[2] * zg + th[3];
        float g1 = th[4] * xg + th[5] * yg + th[6] * zg + th[7];
        float g2 = th[8] * xg + th[9] * yg + th[10] * zg + th[11];
        float ix = (g0 + 1.f) * 0.5f * 99.f;
        float iy = (g1 + 1.f) * 0.5f * 7.f;
        float iz = (g2 + 1.f) * 0.5f * 99.f;
        float x0 = floorf(ix), y0 = floorf(iy), z0 = floorf(iz);
        float wx1 = ix - x0, wy1 = iy - y0, wz1 = iz - z0;
        float wx0 = 1.f - wx1, wy0 = 1.f - wy1, wz0 = 1.f - wz1;

        float w8[8];
        int off8[8];
#pragma unroll
        for (int k = 0; k < 8; ++k) {
            float xf = x0 + (float)(k & 1);
            float yf = y0 + (float)((k >> 1) & 1);
            float zf = z0 + (float)(k >> 2);
            bool valid = (xf >= 0.f) & (xf <= 99.f) &
                         (yf >= 0.f) & (yf <= 7.f) &
                         (zf >= 0.f) & (zf <= 99.f);
            int xi = (int)fminf(fmaxf(xf, 0.f), 99.f);
            int yi = (int)fminf(fmaxf(yf, 0.f), 7.f);
            int zi = (int)fminf(fmaxf(zf, 0.f), 99.f);
            float w = ((k & 1) ? wx1 : wx0) * (((k >> 1) & 1) ? wy1 : wy0) *
                      ((k >> 2) ? wz1 : wz0);
            w8[k] = valid ? w : 0.f;
            off8[k] = (zi * GZ + yi) * GY + xi;  // voxel index in [vid] space
        }

        const unsigned short* hb = h + (size_t)(b * NT + t) * NVOX * OC;
        float sval[OC];
#pragma unroll
        for (int o2 = 0; o2 < OC; ++o2) sval[o2] = 0.f;
#pragma unroll
        for (int k = 0; k < 8; ++k) {
            float w = w8[k];
            const uint4* cp =
                reinterpret_cast<const uint4*>(hb + (size_t)off8[k] * OC);
            uint4 a0 = cp[0], a1 = cp[1], a2 = cp[2], a3 = cp[3], a4 = cp[4];
            unsigned int uu[20] = {a0.x, a0.y, a0.z, a0.w, a1.x, a1.y, a1.z, a1.w,
                                   a2.x, a2.y, a2.z, a2.w, a3.x, a3.y, a3.z, a3.w,
                                   a4.x, a4.y, a4.z, a4.w};
#pragma unroll
            for (int j = 0; j < 20; ++j) {
                sval[2 * j + 0] = fmaf(w, bf_lo(uu[j]), sval[2 * j + 0]);
                sval[2 * j + 1] = fmaf(w, bf_hi(uu[j]), sval[2 * j + 1]);
            }
        }

        // acc[o] += W_T[o, t*40 + o2] * sval[o2]
#pragma unroll
        for (int o = 0; o < OC; ++o) {
            const float4* w4 =
                reinterpret_cast<const float4*>(W_T + o * (NT * OC) + t * OC);
#pragma unroll
            for (int q = 0; q < 10; ++q) {
                float4 w = w4[q];
                acc[o] = fmaf(w.x, sval[4 * q + 0], acc[o]);
                acc[o] = fmaf(w.y, sval[4 * q + 1], acc[o]);
                acc[o] = fmaf(w.z, sval[4 * q + 2], acc[o]);
                acc[o] = fmaf(w.w, sval[4 * q + 3], acc[o]);
            }
        }
    }

    // ---- t = 2: identity grid -> exact pass-through (single 80B load) ----
    {
        const uint4* cp = reinterpret_cast<const uint4*>(
            h + ((size_t)(b * NT + 2) * NVOX + (size_t)vid) * OC);
        uint4 a0 = cp[0], a1 = cp[1], a2 = cp[2], a3 = cp[3], a4 = cp[4];
        unsigned int uu[20] = {a0.x, a0.y, a0.z, a0.w, a1.x, a1.y, a1.z, a1.w,
                               a2.x, a2.y, a2.z, a2.w, a3.x, a3.y, a3.z, a3.w,
                               a4.x, a4.y, a4.z, a4.w};
        float sval[OC];
#pragma unroll
        for (int j = 0; j < 20; ++j) {
            sval[2 * j + 0] = bf_lo(uu[j]);
            sval[2 * j + 1] = bf_hi(uu[j]);
        }
#pragma unroll
        for (int o = 0; o < OC; ++o) {
            const float4* w4 =
                reinterpret_cast<const float4*>(W_T + o * (NT * OC) + 2 * OC);
#pragma unroll
            for (int q = 0; q < 10; ++q) {
                float4 w = w4[q];
                acc[o] = fmaf(w.x, sval[4 * q + 0], acc[o]);
                acc[o] = fmaf(w.y, sval[4 * q + 1], acc[o]);
                acc[o] = fmaf(w.z, sval[4 * q + 2], acc[o]);
                acc[o] = fmaf(w.w, sval[4 * q + 3], acc[o]);
            }
        }
    }

    // per-o planes: lanes have consecutive vid -> coalesced per o
    float* op = out + (size_t)b * OC * NVOX + vid;
#pragma unroll
    for (int o = 0; o < OC; ++o) op[(size_t)o * NVOX] = fmaxf(acc[o], 0.f);
}

extern "C" void kernel_launch(void* const* d_in, const int* in_sizes, int n_in,
                              void* d_out, int out_size, void* d_ws, size_t ws_size,
                              hipStream_t stream) {
    const float* frustum = (const float*)d_in[0];
    const float* RT      = (const float*)d_in[1];
    const float* intrins = (const float*)d_in[2];
    const float* DoF     = (const float*)d_in[3];
    const float* W_N     = (const float*)d_in[4];
    const float* b_N     = (const float*)d_in[5];
    const float* W_T     = (const float*)d_in[6];
    const float* b_T     = (const float*)d_in[7];
    float* out = (float*)d_out;

    const size_t ft_f32  = FT_ELEMS * sizeof(float);          // ~170 MB
    const size_t ft_bf16 = FT_ELEMS * sizeof(unsigned short); // ~85 MB
    const size_t h_bytes = HSZ * sizeof(unsigned short);      // ~38.4 MB
    const size_t small = 4096;                                // P + theta

    char* base = (char*)d_ws;
    int mode;  // 0 = fp32 chlast, 1 = bf16 chlast, 2 = no transpose
    size_t ft_bytes;
    if (ws_size >= ft_f32 + h_bytes + small) { mode = 0; ft_bytes = ft_f32; }
    else if (ws_size >= ft_bf16 + h_bytes + small) { mode = 1; ft_bytes = ft_bf16; }
    else { mode = 2; ft_bytes = 0; }

    size_t ft_al = (ft_bytes + 255) & ~(size_t)255;
    void* ft_buf = base;
    unsigned short* h_buf = (unsigned short*)(base + ft_al);
    float* P_buf = (float*)(base + ft_al + ((h_bytes + 255) & ~(size_t)255));
    float* th_buf = P_buf + NB * NT * NCAM * 12;

    const int tr_blocks = (NB * NT * NCAM * FSZ) / 256;  // 10368
    const int n1_blocks = (NB * NT * NVOX) / 256;        // 1875
    const int n2_blocks = (NB * NVOX) / 256;             // 625

    if (mode == 0) {
        transpose_feat<float><<<tr_blocks, 256, 0, stream>>>(
            frustum, (float*)ft_buf, RT, intrins, DoF, P_buf, th_buf);
        sample_mlp1<float, true><<<n1_blocks, 256, 0, stream>>>(
            frustum, (const float*)ft_buf, P_buf, W_N, b_N, h_buf);
    } else if (mode == 1) {
        transpose_feat<unsigned short><<<tr_blocks, 256, 0, stream>>>(
            frustum, (unsigned short*)ft_buf, RT, intrins, DoF, P_buf, th_buf);
        sample_mlp1<unsigned short, true><<<n1_blocks, 256, 0, stream>>>(
            frustum, (const unsigned short*)ft_buf, P_buf, W_N, b_N, h_buf);
    } else {
        setup_kernel<<<1, 128, 0, stream>>>(RT, intrins, DoF, P_buf, th_buf);
        sample_mlp1<float, false><<<n1_blocks, 256, 0, stream>>>(
            frustum, (const float*)nullptr, P_buf, W_N, b_N, h_buf);
    }

    warp_mlp2<<<n2_blocks, 256, 0, stream>>>(h_buf, th_buf, W_T, b_T, out);
}

// Round 7
// 414.123 us; speedup vs baseline: 1.4020x; 1.1049x over previous
//
#include <hip/hip_runtime.h>

// ---- problem constants (from reference) ----
#define NB 2
#define NT 3
#define NCAM 6
#define NC 16
#define FD 48
#define FH 24
#define FW 64
#define GX 100
#define GY 100
#define GZ 8
#define OC 40
#define NVOX (GX * GY * GZ)          // 80000  (divisible by 64 -> bt, b wave-uniform)
#define FSZ (FD * FH * FW)           // 73728 voxels per channel volume
#define CAMSZ (NC * FSZ)             // per-camera feature volume (orig layout)
#define BTSZ (NCAM * CAMSZ)          // per-(b,t) feature block (orig layout)
#define HSZ ((size_t)NB * NT * OC * NVOX)             // 19,200,000 elems
#define FT_ELEMS ((size_t)NB * NT * NCAM * FSZ * NC)  // 42,467,328

static __device__ __forceinline__ unsigned short f2bf_rne(float x) {
    unsigned int u = __float_as_uint(x);
    unsigned int r = (u + 0x7fffu + ((u >> 16) & 1u)) >> 16;
    return (unsigned short)r;
}
static __device__ __forceinline__ float bf_lo(unsigned int u) {
    return __uint_as_float(u << 16);
}
static __device__ __forceinline__ float bf_hi(unsigned int u) {
    return __uint_as_float(u & 0xffff0000u);
}

// Bijective XCD-aware block swizzle (contiguous chunk per XCD; m204 form).
// warp_mlp2 only. R5 evidence: FETCH 75->20 MB (keep), dur unchanged (the
// kernel is L2-latency-bound, not HBM-bound).
static __device__ __forceinline__ int xcd_swizzle(int bid, int nwg) {
    int xcd = bid & 7;
    int local = bid >> 3;
    int q = nwg >> 3, r = nwg & 7;
    return (xcd < r ? xcd * (q + 1) : r * (q + 1) + (xcd - r) * q) + local;
}

// ----------------------------------------------------------------------------
// Setup math (device helper): P[b,t,n] = intrins[b] @ RT[b,t,n][:3,:]  (3x4)
// theta[b,t] cumulative affine (3x4): t=2 -> I, t=1 -> M4[b,1],
// t=0 -> M4[b,0] @ M4[b,1]
// ----------------------------------------------------------------------------
static __device__ __forceinline__ void do_setup(
    int tid, const float* __restrict__ RT, const float* __restrict__ intrins,
    const float* __restrict__ DoF, float* __restrict__ P,
    float* __restrict__ theta) {
    if (tid < NB * NT * NCAM) {
        int bt = tid / NCAM;
        int b = bt / NT;
        const float* I3 = intrins + b * 9;
        const float* R = RT + (size_t)tid * 16;
        float* Pp = P + tid * 12;
        for (int r = 0; r < 3; ++r)
            for (int c = 0; c < 4; ++c) {
                float s = 0.f;
                for (int k = 0; k < 3; ++k) s += I3[r * 3 + k] * R[k * 4 + c];
                Pp[r * 4 + c] = s;
            }
    }
    if (tid >= 64 && tid < 64 + NB) {
        int b = tid - 64;
        const float* D0 = DoF + (size_t)(b * NT + 0) * 16;
        const float* D1 = DoF + (size_t)(b * NT + 1) * 16;
        float* th = theta + (size_t)b * NT * 12;
        for (int i = 0; i < 12; ++i) th[2 * 12 + i] = 0.f;
        th[2 * 12 + 0] = 1.f; th[2 * 12 + 5] = 1.f; th[2 * 12 + 10] = 1.f;
        for (int i = 0; i < 12; ++i) th[1 * 12 + i] = D1[i];
        for (int r = 0; r < 3; ++r)
            for (int c = 0; c < 4; ++c) {
                float s = (c == 3) ? D0[r * 4 + 3] : 0.f;
                for (int k = 0; k < 3; ++k) s += D0[r * 4 + k] * D1[k * 4 + c];
                th[0 * 12 + r * 4 + c] = s;
            }
    }
}

__global__ void setup_kernel(const float* __restrict__ RT,
                             const float* __restrict__ intrins,
                             const float* __restrict__ DoF,
                             float* __restrict__ P,
                             float* __restrict__ theta) {
    do_setup(threadIdx.x, RT, intrins, DoF, P, theta);
}

// ----------------------------------------------------------------------------
// Transpose features (B,T,N,C,FD,FH,FW) -> [btn][pos][C16] channel-last
// (fp32 or bf16 output). Block 0 additionally performs setup (fused dispatch;
// sample_mlp1 only launches after this kernel completes, so P/theta are ready).
// ----------------------------------------------------------------------------
template <typename FT>
__global__ __launch_bounds__(256) void transpose_feat(
    const float* __restrict__ feat, FT* __restrict__ ft,
    const float* __restrict__ RT, const float* __restrict__ intrins,
    const float* __restrict__ DoF, float* __restrict__ P,
    float* __restrict__ theta) {
    if (blockIdx.x == 0) do_setup(threadIdx.x, RT, intrins, DoF, P, theta);
    size_t tid = (size_t)blockIdx.x * 256 + threadIdx.x;
    int pos = (int)(tid % FSZ);
    int btn = (int)(tid / FSZ);
    const float* src = feat + (size_t)btn * CAMSZ + pos;
    float v[NC];
#pragma unroll
    for (int c = 0; c < NC; ++c) v[c] = src[(size_t)c * FSZ];
    if constexpr (sizeof(FT) == 4) {
        float4* dst = reinterpret_cast<float4*>(
            (float*)ft + ((size_t)btn * FSZ + pos) * NC);
#pragma unroll
        for (int q = 0; q < 4; ++q)
            dst[q] = make_float4(v[4 * q], v[4 * q + 1], v[4 * q + 2], v[4 * q + 3]);
    } else {
        unsigned int packed[8];
#pragma unroll
        for (int j = 0; j < 8; ++j)
            packed[j] = (unsigned int)f2bf_rne(v[2 * j]) |
                        ((unsigned int)f2bf_rne(v[2 * j + 1]) << 16);
        uint4* dst = reinterpret_cast<uint4*>(
            (unsigned short*)ft + ((size_t)btn * FSZ + pos) * NC);
        dst[0] = make_uint4(packed[0], packed[1], packed[2], packed[3]);
        dst[1] = make_uint4(packed[4], packed[5], packed[6], packed[7]);
    }
}

// ----------------------------------------------------------------------------
// Kernel 1: frustum trilinear sample (6 cams x 16 ch) + W_N matvec + ReLU,
// then W_T-HOIST: store g_t = W_T[:, t*40:(t+1)*40] @ relu(acc)  (bf16).
// grid_sample is linear in channels, so W_T commutes with the warp gather --
// this moves warp_mlp2's dominant 40x40 matvec into this 3x-larger grid.
// One thread per (b,t,voxel), sequential 6-cam loop, fp32 float4 gather
// (bf16 gather regressed: VALU unpack), per-cam validity early-out (~75% of
// voxels outside every cam's frustum -> wave-coherent skip).
// g layout: [bt][vid][OC] bf16  (vid = gx*GZ*GY + gz*GY + gy)
// ----------------------------------------------------------------------------
template <typename FT, bool CHLAST>
__global__ __launch_bounds__(256) void sample_mlp1(
    const float* __restrict__ feat,   // original layout (used when !CHLAST)
    const FT* __restrict__ ft,        // channel-last (used when CHLAST)
    const float* __restrict__ P,
    const float* __restrict__ W_N,
    const float* __restrict__ b_N,
    const float* __restrict__ W_T,
    unsigned short* __restrict__ g) {
    int tid = blockIdx.x * 256 + threadIdx.x;
    int vid = tid % NVOX;
    int bt = __builtin_amdgcn_readfirstlane(tid / NVOX);  // wave-uniform (NVOX%64==0)
    int gy = vid % GY;
    int r2 = vid / GY;
    int gz = r2 % GZ;
    int gx = r2 / GZ;
    float X = (float)gx - 49.5f;
    float Y = (float)gy - 49.5f;
    float Z = (float)gz - 2.5f;

    float acc[OC];
#pragma unroll
    for (int o = 0; o < OC; ++o) acc[o] = b_N[o];

    for (int n = 0; n < NCAM; ++n) {
        const float* Pp = P + (bt * NCAM + n) * 12;
        float px = Pp[0] * X + Pp[1] * Y + Pp[2] * Z + Pp[3];
        float py = Pp[4] * X + Pp[5] * Y + Pp[6] * Z + Pp[7];
        float pz = Pp[8] * X + Pp[9] * Y + Pp[10] * Z + Pp[11];
        float zc = fmaxf(pz, 1e-5f);
        float ix = px / zc;                       // = u (normalization round-trips)
        float iy = py / zc;
        float iz = (pz - 2.0f) * (48.0f / 44.8f); // = dbin

        // exact early-out: outside the open box, every corner weight is zero
        bool cam_valid = (ix > -1.f) & (ix < (float)FW) &
                         (iy > -1.f) & (iy < (float)FH) &
                         (iz > -1.f) & (iz < (float)FD);
        if (!cam_valid) continue;

        float x0 = floorf(ix), y0 = floorf(iy), z0 = floorf(iz);
        float wx1 = ix - x0, wy1 = iy - y0, wz1 = iz - z0;
        float wx0 = 1.f - wx1, wy0 = 1.f - wy1, wz0 = 1.f - wz1;

        float w8[8];
        int off8[8];
#pragma unroll
        for (int k = 0; k < 8; ++k) {
            float xf = x0 + (float)(k & 1);
            float yf = y0 + (float)((k >> 1) & 1);
            float zf = z0 + (float)(k >> 2);
            bool valid = (xf >= 0.f) & (xf <= (float)(FW - 1)) &
                         (yf >= 0.f) & (yf <= (float)(FH - 1)) &
                         (zf >= 0.f) & (zf <= (float)(FD - 1));
            int xi = (int)fminf(fmaxf(xf, 0.f), (float)(FW - 1));
            int yi = (int)fminf(fmaxf(yf, 0.f), (float)(FH - 1));
            int zi = (int)fminf(fmaxf(zf, 0.f), (float)(FD - 1));
            float w = ((k & 1) ? wx1 : wx0) * (((k >> 1) & 1) ? wy1 : wy0) *
                      ((k >> 2) ? wz1 : wz0);
            w8[k] = valid ? w : 0.f;
            off8[k] = (zi * FH + yi) * FW + xi;
        }

        float s[NC];
#pragma unroll
        for (int c = 0; c < NC; ++c) s[c] = 0.f;

        if constexpr (CHLAST) {
            const size_t camBase = (size_t)(bt * NCAM + n) * FSZ;
            if constexpr (sizeof(FT) == 4) {
#pragma unroll
                for (int k = 0; k < 8; ++k) {
                    float w = w8[k];
                    const float4* cp = reinterpret_cast<const float4*>(
                        (const float*)ft + (camBase + (size_t)off8[k]) * NC);
#pragma unroll
                    for (int q = 0; q < 4; ++q) {
                        float4 v = cp[q];
                        s[4 * q + 0] = fmaf(w, v.x, s[4 * q + 0]);
                        s[4 * q + 1] = fmaf(w, v.y, s[4 * q + 1]);
                        s[4 * q + 2] = fmaf(w, v.z, s[4 * q + 2]);
                        s[4 * q + 3] = fmaf(w, v.w, s[4 * q + 3]);
                    }
                }
            } else {
#pragma unroll
                for (int k = 0; k < 8; ++k) {
                    float w = w8[k];
                    const uint4* cp = reinterpret_cast<const uint4*>(
                        (const unsigned short*)ft + (camBase + (size_t)off8[k]) * NC);
                    uint4 a = cp[0], b2 = cp[1];
                    unsigned int uu[8] = {a.x, a.y, a.z, a.w, b2.x, b2.y, b2.z, b2.w};
#pragma unroll
                    for (int j = 0; j < 8; ++j) {
                        s[2 * j + 0] = fmaf(w, bf_lo(uu[j]), s[2 * j + 0]);
                        s[2 * j + 1] = fmaf(w, bf_hi(uu[j]), s[2 * j + 1]);
                    }
                }
            }
        } else {
            const float* fn = feat + (size_t)bt * BTSZ + (size_t)n * CAMSZ;
#pragma unroll
            for (int c = 0; c < NC; ++c) {
                const float* fc = fn + (size_t)c * FSZ;
                float v = 0.f;
#pragma unroll
                for (int k = 0; k < 8; ++k) v = fmaf(w8[k], fc[off8[k]], v);
                s[c] = v;
            }
        }

        // acc[o] += W_N[o, n*16 + c] * s[c]
#pragma unroll
        for (int o = 0; o < OC; ++o) {
            const float4* w4 =
                reinterpret_cast<const float4*>(W_N + o * (NCAM * NC) + n * NC);
#pragma unroll
            for (int q = 0; q < 4; ++q) {
                float4 w = w4[q];
                acc[o] = fmaf(w.x, s[4 * q + 0], acc[o]);
                acc[o] = fmaf(w.y, s[4 * q + 1], acc[o]);
                acc[o] = fmaf(w.z, s[4 * q + 2], acc[o]);
                acc[o] = fmaf(w.w, s[4 * q + 3], acc[o]);
            }
        }
    }

    // ReLU (this is h), then hoisted W_T-block matvec: g = W_T[:, t*40:] @ h.
    // Computed 8 outputs at a time to keep the live set small (R4 spill lesson).
#pragma unroll
    for (int o = 0; o < OC; ++o) acc[o] = fmaxf(acc[o], 0.f);

    const int t = bt % NT;  // wave-uniform
    const float* Wtb = W_T + t * OC;            // row o at Wtb + o*(NT*OC)
    uint4* d4 = reinterpret_cast<uint4*>(
        g + ((size_t)bt * NVOX + (size_t)vid) * OC);
#pragma unroll
    for (int grp = 0; grp < 5; ++grp) {
        float g8[8];
#pragma unroll
        for (int j = 0; j < 8; ++j) {
            const float4* w4 = reinterpret_cast<const float4*>(
                Wtb + (size_t)(grp * 8 + j) * (NT * OC));
            float s0 = 0.f;
#pragma unroll
            for (int q = 0; q < 10; ++q) {
                float4 w = w4[q];
                s0 = fmaf(w.x, acc[4 * q + 0], s0);
                s0 = fmaf(w.y, acc[4 * q + 1], s0);
                s0 = fmaf(w.z, acc[4 * q + 2], s0);
                s0 = fmaf(w.w, acc[4 * q + 3], s0);
            }
            g8[j] = s0;
        }
        unsigned int u0 = (unsigned int)f2bf_rne(g8[0]) |
                          ((unsigned int)f2bf_rne(g8[1]) << 16);
        unsigned int u1 = (unsigned int)f2bf_rne(g8[2]) |
                          ((unsigned int)f2bf_rne(g8[3]) << 16);
        unsigned int u2 = (unsigned int)f2bf_rne(g8[4]) |
                          ((unsigned int)f2bf_rne(g8[5]) << 16);
        unsigned int u3 = (unsigned int)f2bf_rne(g8[6]) |
                          ((unsigned int)f2bf_rne(g8[7]) << 16);
        d4[grp] = make_uint4(u0, u1, u2, u3);
    }
}

// ----------------------------------------------------------------------------
// Kernel 2: temporal warp, POST-HOIST: out = relu(gather_t0(g0) + gather_t1(g1)
// + g2[vid] + b_T). No matvec here anymore -- per-thread work dropped from
// ~5800 to ~1100 VALU ops; all t contributions accumulate into one sval[40].
// t=2 theta == I -> exact pass-through (single 80B load).
// out layout: [b][o][d][h][w] = (B,40,100,8,100)
// ----------------------------------------------------------------------------
__global__ __launch_bounds__(256) void warp_mlp2(
    const unsigned short* __restrict__ g,
    const float* __restrict__ theta,
    const float* __restrict__ b_T,
    float* __restrict__ out) {
    int bid = xcd_swizzle(blockIdx.x, gridDim.x);
    int tid = bid * 256 + threadIdx.x;
    int vid = tid % NVOX;
    int b = __builtin_amdgcn_readfirstlane(tid / NVOX);  // wave-uniform
    int w_ = vid % GY;        // Wp = 100
    int r2 = vid / GY;
    int h_ = r2 % GZ;         // Hp = 8
    int d_ = r2 / GZ;         // Dp = 100

    float xg = -1.f + 2.f * (float)w_ / 99.f;
    float yg = -1.f + 2.f * (float)h_ / 7.f;
    float zg = -1.f + 2.f * (float)d_ / 99.f;

    float sval[OC];
#pragma unroll
    for (int o = 0; o < OC; ++o) sval[o] = b_T[o];

    // ---- t = 0, 1: trilinear gather of g_t, accumulated into sval ----
    for (int t = 0; t < 2; ++t) {
        const float* th = theta + (b * NT + t) * 12;
        float g0 = th[0] * xg + th[1] * yg + th[2] * zg + th[3];
        float g1 = th[4] * xg + th[5] * yg + th[6] * zg + th[7];
        float g2 = th[8] * xg + th[9] * yg + th[10] * zg + th[11];
        float ix = (g0 + 1.f) * 0.5f * 99.f;
        float iy = (g1 + 1.f) * 0.5f * 7.f;
        float iz = (g2 + 1.f) * 0.5f * 99.f;
        float x0 = floorf(ix), y0 = floorf(iy), z0 = floorf(iz);
        float wx1 = ix - x0, wy1 = iy - y0, wz1 = iz - z0;
        float wx0 = 1.f - wx1, wy0 = 1.f - wy1, wz0 = 1.f - wz1;

        float w8[8];
        int off8[8];
#pragma unroll
        for (int k = 0; k < 8; ++k) {
            float xf = x0 + (float)(k & 1);
            float yf = y0 + (float)((k >> 1) & 1);
            float zf = z0 + (float)(k >> 2);
            bool valid = (xf >= 0.f) & (xf <= 99.f) &
                         (yf >= 0.f) & (yf <= 7.f) &
                         (zf >= 0.f) & (zf <= 99.f);
            int xi = (int)fminf(fmaxf(xf, 0.f), 99.f);
            int yi = (int)fminf(fmaxf(yf, 0.f), 7.f);
            int zi = (int)fminf(fmaxf(zf, 0.f), 99.f);
            float w = ((k & 1) ? wx1 : wx0) * (((k >> 1) & 1) ? wy1 : wy0) *
                      ((k >> 2) ? wz1 : wz0);
            w8[k] = valid ? w : 0.f;
            off8[k] = (zi * GZ + yi) * GY + xi;  // voxel index in [vid] space
        }

        const unsigned short* hb = g + (size_t)(b * NT + t) * NVOX * OC;
#pragma unroll
        for (int k = 0; k < 8; ++k) {
            float w = w8[k];
            const uint4* cp =
                reinterpret_cast<const uint4*>(hb + (size_t)off8[k] * OC);
            uint4 a0 = cp[0], a1 = cp[1], a2 = cp[2], a3 = cp[3], a4 = cp[4];
            unsigned int uu[20] = {a0.x, a0.y, a0.z, a0.w, a1.x, a1.y, a1.z, a1.w,
                                   a2.x, a2.y, a2.z, a2.w, a3.x, a3.y, a3.z, a3.w,
                                   a4.x, a4.y, a4.z, a4.w};
#pragma unroll
            for (int j = 0; j < 20; ++j) {
                sval[2 * j + 0] = fmaf(w, bf_lo(uu[j]), sval[2 * j + 0]);
                sval[2 * j + 1] = fmaf(w, bf_hi(uu[j]), sval[2 * j + 1]);
            }
        }
    }

    // ---- t = 2: identity grid -> exact pass-through (single 80B load) ----
    {
        const uint4* cp = reinterpret_cast<const uint4*>(
            g + ((size_t)(b * NT + 2) * NVOX + (size_t)vid) * OC);
        uint4 a0 = cp[0], a1 = cp[1], a2 = cp[2], a3 = cp[3], a4 = cp[4];
        unsigned int uu[20] = {a0.x, a0.y, a0.z, a0.w, a1.x, a1.y, a1.z, a1.w,
                               a2.x, a2.y, a2.z, a2.w, a3.x, a3.y, a3.z, a3.w,
                               a4.x, a4.y, a4.z, a4.w};
#pragma unroll
        for (int j = 0; j < 20; ++j) {
            sval[2 * j + 0] += bf_lo(uu[j]);
            sval[2 * j + 1] += bf_hi(uu[j]);
        }
    }

    // per-o planes: lanes have consecutive vid -> coalesced per o
    float* op = out + (size_t)b * OC * NVOX + vid;
#pragma unroll
    for (int o = 0; o < OC; ++o) op[(size_t)o * NVOX] = fmaxf(sval[o], 0.f);
}

extern "C" void kernel_launch(void* const* d_in, const int* in_sizes, int n_in,
                              void* d_out, int out_size, void* d_ws, size_t ws_size,
                              hipStream_t stream) {
    const float* frustum = (const float*)d_in[0];
    const float* RT      = (const float*)d_in[1];
    const float* intrins = (const float*)d_in[2];
    const float* DoF     = (const float*)d_in[3];
    const float* W_N     = (const float*)d_in[4];
    const float* b_N     = (const float*)d_in[5];
    const float* W_T     = (const float*)d_in[6];
    const float* b_T     = (const float*)d_in[7];
    float* out = (float*)d_out;

    const size_t ft_f32  = FT_ELEMS * sizeof(float);          // ~170 MB
    const size_t ft_bf16 = FT_ELEMS * sizeof(unsigned short); // ~85 MB
    const size_t h_bytes = HSZ * sizeof(unsigned short);      // ~38.4 MB
    const size_t small = 4096;                                // P + theta

    char* base = (char*)d_ws;
    int mode;  // 0 = fp32 chlast, 1 = bf16 chlast, 2 = no transpose
    size_t ft_bytes;
    if (ws_size >= ft_f32 + h_bytes + small) { mode = 0; ft_bytes = ft_f32; }
    else if (ws_size >= ft_bf16 + h_bytes + small) { mode = 1; ft_bytes = ft_bf16; }
    else { mode = 2; ft_bytes = 0; }

    size_t ft_al = (ft_bytes + 255) & ~(size_t)255;
    void* ft_buf = base;
    unsigned short* g_buf = (unsigned short*)(base + ft_al);
    float* P_buf = (float*)(base + ft_al + ((h_bytes + 255) & ~(size_t)255));
    float* th_buf = P_buf + NB * NT * NCAM * 12;

    const int tr_blocks = (NB * NT * NCAM * FSZ) / 256;  // 10368
    const int n1_blocks = (NB * NT * NVOX) / 256;        // 1875
    const int n2_blocks = (NB * NVOX) / 256;             // 625

    if (mode == 0) {
        transpose_feat<float><<<tr_blocks, 256, 0, stream>>>(
            frustum, (float*)ft_buf, RT, intrins, DoF, P_buf, th_buf);
        sample_mlp1<float, true><<<n1_blocks, 256, 0, stream>>>(
            frustum, (const float*)ft_buf, P_buf, W_N, b_N, W_T, g_buf);
    } else if (mode == 1) {
        transpose_feat<unsigned short><<<tr_blocks, 256, 0, stream>>>(
            frustum, (unsigned short*)ft_buf, RT, intrins, DoF, P_buf, th_buf);
        sample_mlp1<unsigned short, true><<<n1_blocks, 256, 0, stream>>>(
            frustum, (const unsigned short*)ft_buf, P_buf, W_N, b_N, W_T, g_buf);
    } else {
        setup_kernel<<<1, 128, 0, stream>>>(RT, intrins, DoF, P_buf, th_buf);
        sample_mlp1<float, false><<<n1_blocks, 256, 0, stream>>>(
            frustum, (const float*)nullptr, P_buf, W_N, b_N, W_T, g_buf);
    }

    warp_mlp2<<<n2_blocks, 256, 0, stream>>>(g_buf, th_buf, b_T, out);
}

// Round 8
// 388.614 us; speedup vs baseline: 1.4940x; 1.0656x over previous
//
#include <hip/hip_runtime.h>

// ---- problem constants (from reference) ----
#define NB 2
#define NT 3
#define NCAM 6
#define NC 16
#define FD 48
#define FH 24
#define FW 64
#define GX 100
#define GY 100
#define GZ 8
#define OC 40
#define NVOX (GX * GY * GZ)          // 80000  (divisible by 64 -> bt, b wave-uniform)
#define FSZ (FD * FH * FW)           // 73728 voxels per channel volume
#define CAMSZ (NC * FSZ)             // per-camera feature volume (orig layout)
#define BTSZ (NCAM * CAMSZ)          // per-(b,t) feature block (orig layout)
#define HSZ ((size_t)NB * NT * OC * NVOX)             // 19,200,000 elems
#define FT_ELEMS ((size_t)NB * NT * NCAM * FSZ * NC)  // 42,467,328

static __device__ __forceinline__ unsigned short f2bf_rne(float x) {
    unsigned int u = __float_as_uint(x);
    unsigned int r = (u + 0x7fffu + ((u >> 16) & 1u)) >> 16;
    return (unsigned short)r;
}
static __device__ __forceinline__ float bf_lo(unsigned int u) {
    return __uint_as_float(u << 16);
}
static __device__ __forceinline__ float bf_hi(unsigned int u) {
    return __uint_as_float(u & 0xffff0000u);
}

// Bijective XCD-aware block swizzle (contiguous chunk per XCD; m204 form).
// warp_mlp2 only (R5: FETCH 75->20 MB there).
static __device__ __forceinline__ int xcd_swizzle(int bid, int nwg) {
    int xcd = bid & 7;
    int local = bid >> 3;
    int q = nwg >> 3, r = nwg & 7;
    return (xcd < r ? xcd * (q + 1) : r * (q + 1) + (xcd - r) * q) + local;
}

// ----------------------------------------------------------------------------
// Setup: P[b,t,n] = intrins[b] @ RT[b,t,n][:3,:]  (3x4)
//        theta[b,t] cumulative affine; t=2 -> I
//        g_const[b,t][40] = bf16( W_T[:, t*40:(t+1)*40] @ relu(b_N) )
//        (the sample epilogue output for voxels seen by NO camera)
// ----------------------------------------------------------------------------
static __device__ __forceinline__ void do_setup(
    int tid, const float* __restrict__ RT, const float* __restrict__ intrins,
    const float* __restrict__ DoF, const float* __restrict__ W_T,
    const float* __restrict__ b_N, float* __restrict__ P,
    float* __restrict__ theta, unsigned short* __restrict__ g_const) {
    if (tid < NB * NT * NCAM) {
        int bt = tid / NCAM;
        int b = bt / NT;
        const float* I3 = intrins + b * 9;
        const float* R = RT + (size_t)tid * 16;
        float* Pp = P + tid * 12;
        for (int r = 0; r < 3; ++r)
            for (int c = 0; c < 4; ++c) {
                float s = 0.f;
                for (int k = 0; k < 3; ++k) s += I3[r * 3 + k] * R[k * 4 + c];
                Pp[r * 4 + c] = s;
            }
    }
    if (tid >= 64 && tid < 64 + NB) {
        int b = tid - 64;
        const float* D0 = DoF + (size_t)(b * NT + 0) * 16;
        const float* D1 = DoF + (size_t)(b * NT + 1) * 16;
        float* th = theta + (size_t)b * NT * 12;
        for (int i = 0; i < 12; ++i) th[2 * 12 + i] = 0.f;
        th[2 * 12 + 0] = 1.f; th[2 * 12 + 5] = 1.f; th[2 * 12 + 10] = 1.f;
        for (int i = 0; i < 12; ++i) th[1 * 12 + i] = D1[i];
        for (int r = 0; r < 3; ++r)
            for (int c = 0; c < 4; ++c) {
                float s = (c == 3) ? D0[r * 4 + 3] : 0.f;
                for (int k = 0; k < 3; ++k) s += D0[r * 4 + k] * D1[k * 4 + c];
                th[0 * 12 + r * 4 + c] = s;
            }
    }
    if (tid >= 96 && tid < 96 + NB * NT) {
        int bt = tid - 96;
        int t = bt % NT;
        unsigned short* gc = g_const + (size_t)bt * OC;
        for (int o = 0; o < OC; ++o) {
            float s = 0.f;
            const float* wrow = W_T + (size_t)o * (NT * OC) + t * OC;
            for (int c = 0; c < OC; ++c) s += wrow[c] * fmaxf(b_N[c], 0.f);
            gc[o] = f2bf_rne(s);
        }
    }
}

__global__ void setup_kernel(const float* __restrict__ RT,
                             const float* __restrict__ intrins,
                             const float* __restrict__ DoF,
                             const float* __restrict__ W_T,
                             const float* __restrict__ b_N,
                             float* __restrict__ P,
                             float* __restrict__ theta,
                             unsigned short* __restrict__ g_const) {
    do_setup(threadIdx.x, RT, intrins, DoF, W_T, b_N, P, theta, g_const);
}

// ----------------------------------------------------------------------------
// Transpose features (B,T,N,C,FD,FH,FW) fp32 -> [btn][pos][C16] bf16.
// Block 0 additionally performs setup (fused dispatch).
// ----------------------------------------------------------------------------
__global__ __launch_bounds__(256) void transpose_feat(
    const float* __restrict__ feat, unsigned short* __restrict__ ft,
    const float* __restrict__ RT, const float* __restrict__ intrins,
    const float* __restrict__ DoF, const float* __restrict__ W_T,
    const float* __restrict__ b_N, float* __restrict__ P,
    float* __restrict__ theta, unsigned short* __restrict__ g_const) {
    if (blockIdx.x == 0)
        do_setup(threadIdx.x, RT, intrins, DoF, W_T, b_N, P, theta, g_const);
    size_t tid = (size_t)blockIdx.x * 256 + threadIdx.x;
    int pos = (int)(tid % FSZ);
    int btn = (int)(tid / FSZ);
    const float* src = feat + (size_t)btn * CAMSZ + pos;
    float v[NC];
#pragma unroll
    for (int c = 0; c < NC; ++c) v[c] = src[(size_t)c * FSZ];
    unsigned int packed[8];
#pragma unroll
    for (int j = 0; j < 8; ++j)
        packed[j] = (unsigned int)f2bf_rne(v[2 * j]) |
                    ((unsigned int)f2bf_rne(v[2 * j + 1]) << 16);
    uint4* dst = reinterpret_cast<uint4*>(ft + ((size_t)btn * FSZ + pos) * NC);
    dst[0] = make_uint4(packed[0], packed[1], packed[2], packed[3]);
    dst[1] = make_uint4(packed[4], packed[5], packed[6], packed[7]);
}

// ----------------------------------------------------------------------------
// Kernel 1: frustum trilinear sample (6 cams x 16 ch) + W_N matvec + ReLU,
// + hoisted W_T-block matvec: store g_t = W_T[:, t*40:] @ relu(h)  (bf16).
// bf16 ft gather (2 x uint4 = 32B/corner; whole cam's 8 corners = 64 VGPR of
// load dests -> batchable, vs fp32's 128). Unpack VALU only paid by the ~25%
// valid lanes (R2's bf16 regression was pre-early-out, 100% of lanes).
// Light-thread shortcut: no valid cam -> g row is the per-(b,t) constant
// W_T_t @ relu(b_N), precomputed in setup -> skip the 1600-FMA epilogue.
// ----------------------------------------------------------------------------
template <bool CHLAST>
__global__ __launch_bounds__(256) void sample_mlp1(
    const float* __restrict__ feat,            // original layout (!CHLAST)
    const unsigned short* __restrict__ ft,     // bf16 channel-last (CHLAST)
    const float* __restrict__ P,
    const float* __restrict__ W_N,
    const float* __restrict__ b_N,
    const float* __restrict__ W_T,
    const unsigned short* __restrict__ g_const,
    unsigned short* __restrict__ g) {
    int tid = blockIdx.x * 256 + threadIdx.x;
    int vid = tid % NVOX;
    int bt = __builtin_amdgcn_readfirstlane(tid / NVOX);  // wave-uniform (NVOX%64==0)
    int gy = vid % GY;
    int r2 = vid / GY;
    int gz = r2 % GZ;
    int gx = r2 / GZ;
    float X = (float)gx - 49.5f;
    float Y = (float)gy - 49.5f;
    float Z = (float)gz - 2.5f;

    uint4* d4 = reinterpret_cast<uint4*>(
        g + ((size_t)bt * NVOX + (size_t)vid) * OC);

    float acc[OC];
#pragma unroll
    for (int o = 0; o < OC; ++o) acc[o] = b_N[o];

    bool any_valid = false;

    for (int n = 0; n < NCAM; ++n) {
        const float* Pp = P + (bt * NCAM + n) * 12;
        float px = Pp[0] * X + Pp[1] * Y + Pp[2] * Z + Pp[3];
        float py = Pp[4] * X + Pp[5] * Y + Pp[6] * Z + Pp[7];
        float pz = Pp[8] * X + Pp[9] * Y + Pp[10] * Z + Pp[11];
        float zc = fmaxf(pz, 1e-5f);
        float ix = px / zc;                       // = u (normalization round-trips)
        float iy = py / zc;
        float iz = (pz - 2.0f) * (48.0f / 44.8f); // = dbin

        // exact early-out: outside the open box, every corner weight is zero
        bool cam_valid = (ix > -1.f) & (ix < (float)FW) &
                         (iy > -1.f) & (iy < (float)FH) &
                         (iz > -1.f) & (iz < (float)FD);
        if (!cam_valid) continue;
        any_valid = true;

        float x0 = floorf(ix), y0 = floorf(iy), z0 = floorf(iz);
        float wx1 = ix - x0, wy1 = iy - y0, wz1 = iz - z0;
        float wx0 = 1.f - wx1, wy0 = 1.f - wy1, wz0 = 1.f - wz1;

        float w8[8];
        int off8[8];
#pragma unroll
        for (int k = 0; k < 8; ++k) {
            float xf = x0 + (float)(k & 1);
            float yf = y0 + (float)((k >> 1) & 1);
            float zf = z0 + (float)(k >> 2);
            bool valid = (xf >= 0.f) & (xf <= (float)(FW - 1)) &
                         (yf >= 0.f) & (yf <= (float)(FH - 1)) &
                         (zf >= 0.f) & (zf <= (float)(FD - 1));
            int xi = (int)fminf(fmaxf(xf, 0.f), (float)(FW - 1));
            int yi = (int)fminf(fmaxf(yf, 0.f), (float)(FH - 1));
            int zi = (int)fminf(fmaxf(zf, 0.f), (float)(FD - 1));
            float w = ((k & 1) ? wx1 : wx0) * (((k >> 1) & 1) ? wy1 : wy0) *
                      ((k >> 2) ? wz1 : wz0);
            w8[k] = valid ? w : 0.f;
            off8[k] = (zi * FH + yi) * FW + xi;
        }

        float s[NC];
#pragma unroll
        for (int c = 0; c < NC; ++c) s[c] = 0.f;

        if constexpr (CHLAST) {
            const size_t camBase = (size_t)(bt * NCAM + n) * FSZ;
#pragma unroll
            for (int k = 0; k < 8; ++k) {
                float w = w8[k];
                const uint4* cp = reinterpret_cast<const uint4*>(
                    ft + (camBase + (size_t)off8[k]) * NC);
                uint4 a = cp[0], b2 = cp[1];
                unsigned int uu[8] = {a.x, a.y, a.z, a.w, b2.x, b2.y, b2.z, b2.w};
#pragma unroll
                for (int j = 0; j < 8; ++j) {
                    s[2 * j + 0] = fmaf(w, bf_lo(uu[j]), s[2 * j + 0]);
                    s[2 * j + 1] = fmaf(w, bf_hi(uu[j]), s[2 * j + 1]);
                }
            }
        } else {
            const float* fn = feat + (size_t)bt * BTSZ + (size_t)n * CAMSZ;
#pragma unroll
            for (int c = 0; c < NC; ++c) {
                const float* fc = fn + (size_t)c * FSZ;
                float v = 0.f;
#pragma unroll
                for (int k = 0; k < 8; ++k) v = fmaf(w8[k], fc[off8[k]], v);
                s[c] = v;
            }
        }

        // acc[o] += W_N[o, n*16 + c] * s[c]
#pragma unroll
        for (int o = 0; o < OC; ++o) {
            const float4* w4 =
                reinterpret_cast<const float4*>(W_N + o * (NCAM * NC) + n * NC);
#pragma unroll
            for (int q = 0; q < 4; ++q) {
                float4 w = w4[q];
                acc[o] = fmaf(w.x, s[4 * q + 0], acc[o]);
                acc[o] = fmaf(w.y, s[4 * q + 1], acc[o]);
                acc[o] = fmaf(w.z, s[4 * q + 2], acc[o]);
                acc[o] = fmaf(w.w, s[4 * q + 3], acc[o]);
            }
        }
    }

    // ---- light-thread shortcut: no cam saw this voxel -> constant g row ----
    if (!any_valid) {
        const uint4* gc = reinterpret_cast<const uint4*>(
            g_const + (size_t)bt * OC);
        uint4 r0 = gc[0], r1 = gc[1], r2_ = gc[2], r3 = gc[3], r4 = gc[4];
        d4[0] = r0; d4[1] = r1; d4[2] = r2_; d4[3] = r3; d4[4] = r4;
        return;
    }

    // ReLU (this is h), then hoisted W_T-block matvec: g = W_T[:, t*40:] @ h.
    // 8 outputs at a time to keep the live set small (R4 spill lesson).
#pragma unroll
    for (int o = 0; o < OC; ++o) acc[o] = fmaxf(acc[o], 0.f);

    const int t = bt % NT;  // wave-uniform
    const float* Wtb = W_T + t * OC;            // row o at Wtb + o*(NT*OC)
#pragma unroll
    for (int grp = 0; grp < 5; ++grp) {
        float g8[8];
#pragma unroll
        for (int j = 0; j < 8; ++j) {
            const float4* w4 = reinterpret_cast<const float4*>(
                Wtb + (size_t)(grp * 8 + j) * (NT * OC));
            float s0 = 0.f;
#pragma unroll
            for (int q = 0; q < 10; ++q) {
                float4 w = w4[q];
                s0 = fmaf(w.x, acc[4 * q + 0], s0);
                s0 = fmaf(w.y, acc[4 * q + 1], s0);
                s0 = fmaf(w.z, acc[4 * q + 2], s0);
                s0 = fmaf(w.w, acc[4 * q + 3], s0);
            }
            g8[j] = s0;
        }
        unsigned int u0 = (unsigned int)f2bf_rne(g8[0]) |
                          ((unsigned int)f2bf_rne(g8[1]) << 16);
        unsigned int u1 = (unsigned int)f2bf_rne(g8[2]) |
                          ((unsigned int)f2bf_rne(g8[3]) << 16);
        unsigned int u2 = (unsigned int)f2bf_rne(g8[4]) |
                          ((unsigned int)f2bf_rne(g8[5]) << 16);
        unsigned int u3 = (unsigned int)f2bf_rne(g8[6]) |
                          ((unsigned int)f2bf_rne(g8[7]) << 16);
        d4[grp] = make_uint4(u0, u1, u2, u3);
    }
}

// ----------------------------------------------------------------------------
// Kernel 2: temporal warp, post-hoist: out = relu(gather_t0(g0) + gather_t1(g1)
// + g2[vid] + b_T). t=2 theta == I -> exact pass-through (single 80B load).
// Unchanged from R7. out layout: [b][o][d][h][w] = (B,40,100,8,100)
// ----------------------------------------------------------------------------
__global__ __launch_bounds__(256) void warp_mlp2(
    const unsigned short* __restrict__ g,
    const float* __restrict__ theta,
    const float* __restrict__ b_T,
    float* __restrict__ out) {
    int bid = xcd_swizzle(blockIdx.x, gridDim.x);
    int tid = bid * 256 + threadIdx.x;
    int vid = tid % NVOX;
    int b = __builtin_amdgcn_readfirstlane(tid / NVOX);  // wave-uniform
    int w_ = vid % GY;        // Wp = 100
    int r2 = vid / GY;
    int h_ = r2 % GZ;         // Hp = 8
    int d_ = r2 / GZ;         // Dp = 100

    float xg = -1.f + 2.f * (float)w_ / 99.f;
    float yg = -1.f + 2.f * (float)h_ / 7.f;
    float zg = -1.f + 2.f * (float)d_ / 99.f;

    float sval[OC];
#pragma unroll
    for (int o = 0; o < OC; ++o) sval[o] = b_T[o];

    // ---- t = 0, 1: trilinear gather of g_t, accumulated into sval ----
    for (int t = 0; t < 2; ++t) {
        const float* th = theta + (b * NT + t) * 12;
        float g0 = th[0] * xg + th[1] * yg + th[2] * zg + th[3];
        float g1 = th[4] * xg + th[5] * yg + th[6] * zg + th[7];
        float g2 = th[8] * xg + th[9] * yg + th[10] * zg + th[11];
        float ix = (g0 + 1.f) * 0.5f * 99.f;
        float iy = (g1 + 1.f) * 0.5f * 7.f;
        float iz = (g2 + 1.f) * 0.5f * 99.f;
        float x0 = floorf(ix), y0 = floorf(iy), z0 = floorf(iz);
        float wx1 = ix - x0, wy1 = iy - y0, wz1 = iz - z0;
        float wx0 = 1.f - wx1, wy0 = 1.f - wy1, wz0 = 1.f - wz1;

        float w8[8];
        int off8[8];
#pragma unroll
        for (int k = 0; k < 8; ++k) {
            float xf = x0 + (float)(k & 1);
            float yf = y0 + (float)((k >> 1) & 1);
            float zf = z0 + (float)(k >> 2);
            bool valid = (xf >= 0.f) & (xf <= 99.f) &
                         (yf >= 0.f) & (yf <= 7.f) &
                         (zf >= 0.f) & (zf <= 99.f);
            int xi = (int)fminf(fmaxf(xf, 0.f), 99.f);
            int yi = (int)fminf(fmaxf(yf, 0.f), 7.f);
            int zi = (int)fminf(fmaxf(zf, 0.f), 99.f);
            float w = ((k & 1) ? wx1 : wx0) * (((k >> 1) & 1) ? wy1 : wy0) *
                      ((k >> 2) ? wz1 : wz0);
            w8[k] = valid ? w : 0.f;
            off8[k] = (zi * GZ + yi) * GY + xi;  // voxel index in [vid] space
        }

        const unsigned short* hb = g + (size_t)(b * NT + t) * NVOX * OC;
#pragma unroll
        for (int k = 0; k < 8; ++k) {
            float w = w8[k];
            const uint4* cp =
                reinterpret_cast<const uint4*>(hb + (size_t)off8[k] * OC);
            uint4 a0 = cp[0], a1 = cp[1], a2 = cp[2], a3 = cp[3], a4 = cp[4];
            unsigned int uu[20] = {a0.x, a0.y, a0.z, a0.w, a1.x, a1.y, a1.z, a1.w,
                                   a2.x, a2.y, a2.z, a2.w, a3.x, a3.y, a3.z, a3.w,
                                   a4.x, a4.y, a4.z, a4.w};
#pragma unroll
            for (int j = 0; j < 20; ++j) {
                sval[2 * j + 0] = fmaf(w, bf_lo(uu[j]), sval[2 * j + 0]);
                sval[2 * j + 1] = fmaf(w, bf_hi(uu[j]), sval[2 * j + 1]);
            }
        }
    }

    // ---- t = 2: identity grid -> exact pass-through (single 80B load) ----
    {
        const uint4* cp = reinterpret_cast<const uint4*>(
            g + ((size_t)(b * NT + 2) * NVOX + (size_t)vid) * OC);
        uint4 a0 = cp[0], a1 = cp[1], a2 = cp[2], a3 = cp[3], a4 = cp[4];
        unsigned int uu[20] = {a0.x, a0.y, a0.z, a0.w, a1.x, a1.y, a1.z, a1.w,
                               a2.x, a2.y, a2.z, a2.w, a3.x, a3.y, a3.z, a3.w,
                               a4.x, a4.y, a4.z, a4.w};
#pragma unroll
        for (int j = 0; j < 20; ++j) {
            sval[2 * j + 0] += bf_lo(uu[j]);
            sval[2 * j + 1] += bf_hi(uu[j]);
        }
    }

    // per-o planes: lanes have consecutive vid -> coalesced per o
    float* op = out + (size_t)b * OC * NVOX + vid;
#pragma unroll
    for (int o = 0; o < OC; ++o) op[(size_t)o * NVOX] = fmaxf(sval[o], 0.f);
}

extern "C" void kernel_launch(void* const* d_in, const int* in_sizes, int n_in,
                              void* d_out, int out_size, void* d_ws, size_t ws_size,
                              hipStream_t stream) {
    const float* frustum = (const float*)d_in[0];
    const float* RT      = (const float*)d_in[1];
    const float* intrins = (const float*)d_in[2];
    const float* DoF     = (const float*)d_in[3];
    const float* W_N     = (const float*)d_in[4];
    const float* b_N     = (const float*)d_in[5];
    const float* W_T     = (const float*)d_in[6];
    const float* b_T     = (const float*)d_in[7];
    float* out = (float*)d_out;

    const size_t ft_bytes = FT_ELEMS * sizeof(unsigned short); // ~85 MB
    const size_t g_bytes  = HSZ * sizeof(unsigned short);      // ~38.4 MB
    const size_t small = 4096;                                 // P + theta + g_const

    char* base = (char*)d_ws;
    bool use_ft = ws_size >= ft_bytes + g_bytes + small;

    size_t ft_al = use_ft ? ((ft_bytes + 255) & ~(size_t)255) : 0;
    unsigned short* ft_buf = (unsigned short*)base;
    unsigned short* g_buf = (unsigned short*)(base + ft_al);
    float* P_buf = (float*)(base + ft_al + ((g_bytes + 255) & ~(size_t)255));
    float* th_buf = P_buf + NB * NT * NCAM * 12;              // 432 floats in
    unsigned short* gc_buf = (unsigned short*)(th_buf + NB * NT * 12);

    const int tr_blocks = (NB * NT * NCAM * FSZ) / 256;  // 10368
    const int n1_blocks = (NB * NT * NVOX) / 256;        // 1875
    const int n2_blocks = (NB * NVOX) / 256;             // 625

    if (use_ft) {
        transpose_feat<<<tr_blocks, 256, 0, stream>>>(
            frustum, ft_buf, RT, intrins, DoF, W_T, b_N, P_buf, th_buf, gc_buf);
        sample_mlp1<true><<<n1_blocks, 256, 0, stream>>>(
            frustum, ft_buf, P_buf, W_N, b_N, W_T, gc_buf, g_buf);
    } else {
        setup_kernel<<<1, 128, 0, stream>>>(
            RT, intrins, DoF, W_T, b_N, P_buf, th_buf, gc_buf);
        sample_mlp1<false><<<n1_blocks, 256, 0, stream>>>(
            frustum, (const unsigned short*)nullptr, P_buf, W_N, b_N, W_T,
            gc_buf, g_buf);
    }

    warp_mlp2<<<n2_blocks, 256, 0, stream>>>(g_buf, th_buf, b_T, out);
}